// Round 2
// baseline (290.146 us; speedup 1.0000x reference)
//
#include <hip/hip_runtime.h>
#include <cstdint>
#include <cstddef>

#define BB   32
#define NN   1024
#define FIN  128
#define FOUT 128

typedef __attribute__((ext_vector_type(8))) short bf16x8;
typedef __attribute__((ext_vector_type(4))) float f32x4;

__device__ __forceinline__ unsigned int f2bf(float f) {
    union { float f; unsigned int u; } v; v.f = f;
    unsigned int u = v.u;
    return (u + 0x7FFFu + ((u >> 16) & 1u)) >> 16;   // RNE fp32 -> bf16
}
__device__ __forceinline__ unsigned int pack2(float a, float b) {
    return f2bf(a) | (f2bf(b) << 16);
}

// ---------------------------------------------------------------------------
// Kernel 1: Yt[b][o][m] = sum_f node[b][m][f] * W[o][f]  (bf16, [B][FOUT][NN])
// C[o][m] computed directly in Yt layout: A-frag = W rows (o), B-frag = node
// rows (m).  grid 512 = 32 b x 16 m-tiles(64); block 256 (4 waves, 32 o each).
// All global staging is flat lane-contiguous float4 (fully coalesced).
// ---------------------------------------------------------------------------
__global__ __launch_bounds__(256) void y_kernel(const float* __restrict__ node,
                                                const float* __restrict__ W,
                                                unsigned short* __restrict__ Yt) {
    __shared__ unsigned short Wlds[128 * 136];   // 34816 B  [o][f]
    __shared__ unsigned short Nlds[64 * 136];    // 17408 B  [m][f]

    const int tid = threadIdx.x;
    const int bid = blockIdx.x;
    const int b   = bid >> 4;
    const int m0  = (bid & 15) * 64;

    // stage W [128][128] fp32 -> bf16, flat float4, coalesced
    #pragma unroll
    for (int i = 0; i < 16; ++i) {
        const int idx = i * 256 + tid;            // float4 index
        const int row = idx >> 5;                 // 32 float4 per row
        const int c   = (idx & 31) * 4;           // element col
        float4 v = ((const float4*)W)[idx];
        uint2 p; p.x = pack2(v.x, v.y); p.y = pack2(v.z, v.w);
        *(uint2*)&Wlds[row * 136 + c] = p;
    }
    // stage node tile [64][128] fp32 -> bf16, flat float4, coalesced
    {
        const float* base = node + ((size_t)b * NN + m0) * FIN;
        #pragma unroll
        for (int i = 0; i < 8; ++i) {
            const int idx = i * 256 + tid;
            const int row = idx >> 5;
            const int c   = (idx & 31) * 4;
            float4 v = *(const float4*)(base + row * FIN + c);
            uint2 p; p.x = pack2(v.x, v.y); p.y = pack2(v.z, v.w);
            *(uint2*)&Nlds[row * 136 + c] = p;
        }
    }
    __syncthreads();

    const int w = tid >> 6, lane = tid & 63;
    const int wo = w * 32;                        // 32 o-rows per wave
    const int lcol = lane & 15, lk = (lane >> 4) * 8;

    f32x4 acc[2][4] = {};
    #pragma unroll
    for (int kc = 0; kc < 4; ++kc) {
        const int kof = kc * 32 + lk;
        bf16x8 a[2], bb[4];
        #pragma unroll
        for (int mi = 0; mi < 2; ++mi)
            a[mi] = *(const bf16x8*)&Wlds[(wo + mi*16 + lcol) * 136 + kof];
        #pragma unroll
        for (int ni = 0; ni < 4; ++ni)
            bb[ni] = *(const bf16x8*)&Nlds[(ni*16 + lcol) * 136 + kof];
        #pragma unroll
        for (int mi = 0; mi < 2; ++mi)
            #pragma unroll
            for (int ni = 0; ni < 4; ++ni)
                acc[mi][ni] = __builtin_amdgcn_mfma_f32_16x16x32_bf16(
                    a[mi], bb[ni], acc[mi][ni], 0, 0, 0);
    }
    __syncthreads();   // done reading Wlds; reuse as Ylds

    // C/D frag: col(lane&15)=m, row=(lane>>4)*4+reg=o.  Stage [o][m] stride 72.
    unsigned short* Ylds = Wlds;                  // 128*72*2 = 18432 B, fits
    const int rq = (lane >> 4) * 4;
    #pragma unroll
    for (int mi = 0; mi < 2; ++mi)
        #pragma unroll
        for (int ni = 0; ni < 4; ++ni)
            #pragma unroll
            for (int r = 0; r < 4; ++r) {
                const int o = wo + mi * 16 + rq + r;
                const int m = ni * 16 + lcol;
                Ylds[o * 72 + m] = (unsigned short)f2bf(acc[mi][ni][r]);
            }
    __syncthreads();

    // coalesced store: 8 lanes cover one full 128 B line of an o-row
    {
        const int oq = tid >> 3, c = (tid & 7) * 8;      // 8 bf16 = 16 B
        #pragma unroll
        for (int j = 0; j < 4; ++j) {
            const int o = oq + 32 * j;
            uint4 v = *(const uint4*)&Ylds[o * 72 + c];
            *(uint4*)(Yt + ((size_t)b * FOUT + o) * NN + m0 + c) = v;
        }
    }
}

// ---------------------------------------------------------------------------
// Kernel 2: out[b][n][o] = leaky( (sum_m adj[b][n][m]*Yt[b][o][m]) / rowsum
//                                  + bias[o] )
// grid 1024 = 32 b x 32 n-tiles(32)  -> 4 blocks/CU, 16 waves/CU.
// block 256; tile 32 n x 128 o; BK=64, 16 K-steps; register prefetch;
// rowsum fused into A staging; LDS-staged coalesced epilogue.
// ---------------------------------------------------------------------------
__global__ __launch_bounds__(256, 4) void gcn_kernel(const float* __restrict__ adj,
                                                     const unsigned short* __restrict__ Yt,
                                                     const float* __restrict__ bias,
                                                     float* __restrict__ out) {
    __shared__ char smem[23040];
    unsigned short* Alds = (unsigned short*)smem;           // 32 x 72 bf16
    unsigned short* Blds = (unsigned short*)(smem + 4608);  // 128 x 72 bf16
    float* Clds = (float*)smem;                             // 32 x 136 fp32 (epilogue)
    __shared__ float rs[32];

    const int tid = threadIdx.x;
    const int bid = blockIdx.x;
    const int b   = bid >> 5;
    const int n0  = (bid & 31) * 32;

    const int arow = tid >> 3;           // 0..31
    const int kq   = tid & 7;            // 8 lanes cover 64 k (contiguous)

    const float*          aptr = adj + ((size_t)b * NN + n0 + arow) * NN + kq * 8;
    const unsigned short* bptr = Yt  + ((size_t)b * FOUT + arow) * NN + kq * 8;

    float rsum = 0.f;
    float4 av[2];
    uint4  bv[4];
    #pragma unroll
    for (int j = 0; j < 2; ++j) av[j] = *(const float4*)(aptr + j * 4);
    #pragma unroll
    for (int j = 0; j < 4; ++j) bv[j] = *(const uint4*)(bptr + (size_t)j * 32 * NN);

    const int w = tid >> 6, lane = tid & 63;
    const int wm = (w & 1) * 16, wn = (w >> 1) * 64;
    const int lcol = lane & 15, lk = (lane >> 4) * 8;

    f32x4 acc[4] = {};

    for (int s = 0; s < 16; ++s) {
        // drain prefetched regs into LDS (fp32->bf16 for A, fused rowsum)
        #pragma unroll
        for (int j = 0; j < 2; ++j) {
            float4 v = av[j];
            rsum += (v.x + v.y) + (v.z + v.w);
            uint2 p; p.x = pack2(v.x, v.y); p.y = pack2(v.z, v.w);
            *(uint2*)&Alds[arow * 72 + kq * 8 + j * 4] = p;
        }
        #pragma unroll
        for (int j = 0; j < 4; ++j)
            *(uint4*)&Blds[(arow + 32 * j) * 72 + kq * 8] = bv[j];

        // issue next step's global loads before the barrier
        if (s < 15) {
            const float*          ap = aptr + (s + 1) * 64;
            const unsigned short* bp = bptr + (s + 1) * 64;
            #pragma unroll
            for (int j = 0; j < 2; ++j) av[j] = *(const float4*)(ap + j * 4);
            #pragma unroll
            for (int j = 0; j < 4; ++j) bv[j] = *(const uint4*)(bp + (size_t)j * 32 * NN);
        }
        __syncthreads();

        #pragma unroll
        for (int kc = 0; kc < 2; ++kc) {
            const int kof = kc * 32 + lk;
            bf16x8 af = *(const bf16x8*)&Alds[(wm + lcol) * 72 + kof];
            bf16x8 bf_[4];
            #pragma unroll
            for (int ni = 0; ni < 4; ++ni)
                bf_[ni] = *(const bf16x8*)&Blds[(wn + ni*16 + lcol) * 72 + kof];
            #pragma unroll
            for (int ni = 0; ni < 4; ++ni)
                acc[ni] = __builtin_amdgcn_mfma_f32_16x16x32_bf16(
                    af, bf_[ni], acc[ni], 0, 0, 0);
        }
        __syncthreads();
    }

    // rowsum: 8 consecutive lanes share a row
    rsum += __shfl_xor(rsum, 1);
    rsum += __shfl_xor(rsum, 2);
    rsum += __shfl_xor(rsum, 4);
    if ((tid & 7) == 0) rs[arow] = rsum;
    __syncthreads();   // also: all LDS reads done before Clds aliases Alds/Blds

    // epilogue: scale + bias + leaky, stage to LDS (stride 136 -> 2-way banks)
    const int rq = (lane >> 4) * 4;
    #pragma unroll
    for (int ni = 0; ni < 4; ++ni) {
        const int col = wn + ni * 16 + lcol;
        const float bc = bias[col];
        #pragma unroll
        for (int r = 0; r < 4; ++r) {
            const int row = wm + rq + r;
            float v = acc[ni][r] * (1.0f / rs[row]) + bc;
            v = (v >= 0.f) ? v : 0.01f * v;
            Clds[row * 136 + col] = v;
        }
    }
    __syncthreads();

    // coalesced full-line stores: 32 lanes cover one full 512 B row
    {
        float* outB = out + ((size_t)b * NN + n0) * FOUT;
        #pragma unroll
        for (int i = 0; i < 4; ++i) {
            const int idx = i * 256 + tid;        // float4 index, 32 per row
            const int row = idx >> 5;
            const int c   = (idx & 31) * 4;
            float4 v = *(const float4*)&Clds[row * 136 + c];
            *(float4*)(outB + (size_t)row * FOUT + c) = v;
        }
    }
}

extern "C" void kernel_launch(void* const* d_in, const int* in_sizes, int n_in,
                              void* d_out, int out_size, void* d_ws, size_t ws_size,
                              hipStream_t stream) {
    const float* node = (const float*)d_in[0];   // [32,1024,128]
    const float* adj  = (const float*)d_in[1];   // [32,1024,1024]
    const float* W    = (const float*)d_in[2];   // [128,128]
    const float* bias = (const float*)d_in[3];   // [128]
    float* out = (float*)d_out;                  // [32,1024,128] fp32
    unsigned short* Yt = (unsigned short*)d_ws;  // [32,128,1024] bf16 = 8 MiB

    hipLaunchKernelGGL(y_kernel,   dim3(512),  dim3(256), 0, stream, node, W, Yt);
    hipLaunchKernelGGL(gcn_kernel, dim3(1024), dim3(256), 0, stream, adj, Yt, bias, out);
}

// Round 3
// 226.207 us; speedup vs baseline: 1.2827x; 1.2827x over previous
//
#include <hip/hip_runtime.h>
#include <cstdint>
#include <cstddef>

#define BB   32
#define NN   1024
#define FIN  128
#define FOUT 128

typedef __attribute__((ext_vector_type(8))) short bf16x8;
typedef __attribute__((ext_vector_type(4))) float f32x4;

__device__ __forceinline__ unsigned int f2bf(float f) {
    union { float f; unsigned int u; } v; v.f = f;
    unsigned int u = v.u;
    return (u + 0x7FFFu + ((u >> 16) & 1u)) >> 16;   // RNE fp32 -> bf16
}
__device__ __forceinline__ unsigned int pack2(float a, float b) {
    return f2bf(a) | (f2bf(b) << 16);
}

// async global -> LDS DMA, 16 B per lane; lds dst is wave-uniform base,
// HW scatters lane i to base + i*16 (m97/m104 semantics)
__device__ __forceinline__ void load_lds16(const void* g, void* l) {
    __builtin_amdgcn_global_load_lds(
        (const __attribute__((address_space(1))) unsigned int*)g,
        (__attribute__((address_space(3))) unsigned int*)l, 16, 0, 0);
}

// ---------------------------------------------------------------------------
// Kernel 1: Yt[b][o][m] = sum_f node[b][m][f] * W[o][f]  (bf16, [B][FOUT][NN])
// (unchanged from round 2 — kept as control; diagnose via counters next round)
// ---------------------------------------------------------------------------
__global__ __launch_bounds__(256) void y_kernel(const float* __restrict__ node,
                                                const float* __restrict__ W,
                                                unsigned short* __restrict__ Yt) {
    __shared__ unsigned short Wlds[128 * 136];
    __shared__ unsigned short Nlds[64 * 136];

    const int tid = threadIdx.x;
    const int bid = blockIdx.x;
    const int b   = bid >> 4;
    const int m0  = (bid & 15) * 64;

    #pragma unroll
    for (int i = 0; i < 16; ++i) {
        const int idx = i * 256 + tid;
        const int row = idx >> 5;
        const int c   = (idx & 31) * 4;
        float4 v = ((const float4*)W)[idx];
        uint2 p; p.x = pack2(v.x, v.y); p.y = pack2(v.z, v.w);
        *(uint2*)&Wlds[row * 136 + c] = p;
    }
    {
        const float* base = node + ((size_t)b * NN + m0) * FIN;
        #pragma unroll
        for (int i = 0; i < 8; ++i) {
            const int idx = i * 256 + tid;
            const int row = idx >> 5;
            const int c   = (idx & 31) * 4;
            float4 v = *(const float4*)(base + row * FIN + c);
            uint2 p; p.x = pack2(v.x, v.y); p.y = pack2(v.z, v.w);
            *(uint2*)&Nlds[row * 136 + c] = p;
        }
    }
    __syncthreads();

    const int w = tid >> 6, lane = tid & 63;
    const int wo = w * 32;
    const int lcol = lane & 15, lk = (lane >> 4) * 8;

    f32x4 acc[2][4] = {};
    #pragma unroll
    for (int kc = 0; kc < 4; ++kc) {
        const int kof = kc * 32 + lk;
        bf16x8 a[2], bb[4];
        #pragma unroll
        for (int mi = 0; mi < 2; ++mi)
            a[mi] = *(const bf16x8*)&Wlds[(wo + mi*16 + lcol) * 136 + kof];
        #pragma unroll
        for (int ni = 0; ni < 4; ++ni)
            bb[ni] = *(const bf16x8*)&Nlds[(ni*16 + lcol) * 136 + kof];
        #pragma unroll
        for (int mi = 0; mi < 2; ++mi)
            #pragma unroll
            for (int ni = 0; ni < 4; ++ni)
                acc[mi][ni] = __builtin_amdgcn_mfma_f32_16x16x32_bf16(
                    a[mi], bb[ni], acc[mi][ni], 0, 0, 0);
    }
    __syncthreads();

    unsigned short* Ylds = Wlds;
    const int rq = (lane >> 4) * 4;
    #pragma unroll
    for (int mi = 0; mi < 2; ++mi)
        #pragma unroll
        for (int ni = 0; ni < 4; ++ni)
            #pragma unroll
            for (int r = 0; r < 4; ++r) {
                const int o = wo + mi * 16 + rq + r;
                const int m = ni * 16 + lcol;
                Ylds[o * 72 + m] = (unsigned short)f2bf(acc[mi][ni][r]);
            }
    __syncthreads();

    {
        const int oq = tid >> 3, c = (tid & 7) * 8;
        #pragma unroll
        for (int j = 0; j < 4; ++j) {
            const int o = oq + 32 * j;
            uint4 v = *(const uint4*)&Ylds[o * 72 + c];
            *(uint4*)(Yt + ((size_t)b * FOUT + o) * NN + m0 + c) = v;
        }
    }
}

// ---------------------------------------------------------------------------
// Kernel 2 (m97-style): out = leaky( (adj @ Yt^T) / rowsum(adj) + bias )
// grid 1024 = 32 b x 32 n-tiles(32); block 256 (4 waves, 2x2 over 32x128).
// Single-buffered LDS filled by global_load_lds x16B (async DMA); fp32->bf16
// convert + rowsum fused into the LDS->fragment path; XOR chunk swizzle on
// the DMA source address kills the 16-way fragment-read bank conflict.
// LDS 24.7 KB -> ~4-6 blocks/CU.
// ---------------------------------------------------------------------------
__global__ __launch_bounds__(256, 4) void gcn_kernel(const float* __restrict__ adj,
                                                     const unsigned short* __restrict__ Yt,
                                                     const float* __restrict__ bias,
                                                     float* __restrict__ out) {
    __shared__ char smem[24576 + 128];
    float* Afp          = (float*)smem;                  // [32][64] fp32, raw
    float* Clds         = (float*)smem;                  // epilogue [32][132]
    float* rs           = (float*)(smem + 24576);        // [32]
    // Bbf = smem+8192: [128][64] bf16, raw

    const int tid  = threadIdx.x;
    const int lane = tid & 63;
    const int w    = tid >> 6;
    const int bid  = blockIdx.x;
    const int b    = bid >> 5;
    const int n0   = (bid & 31) * 32;

    // ---- DMA pointers (source carries the XOR chunk swizzle) ----
    // A: tile 32 rows x 64 fp32 = 512 chunks(16B); 2 instrs/wave.
    const float* aSrc[2];
    char*        aDst[2];
    #pragma unroll
    for (int j = 0; j < 2; ++j) {
        const int s = (w * 2 + j) * 64 + lane;           // slot
        const int r = s >> 4, c = s & 15;
        const int g = c ^ (r & 7);                       // fetched data chunk
        aSrc[j] = adj + ((size_t)(b * NN + n0 + r)) * NN + g * 4;
        aDst[j] = smem + (w * 2 + j) * 1024;
    }
    // B: tile 128 rows x 64 bf16 = 1024 chunks; 4 instrs/wave.
    const unsigned short* bSrc[4];
    char*                 bDst[4];
    #pragma unroll
    for (int j = 0; j < 4; ++j) {
        const int s = (w * 4 + j) * 64 + lane;
        const int o = s >> 3, c = s & 7;
        const int g = c ^ (o & 7);
        bSrc[j] = Yt + ((size_t)(b * FOUT + o)) * NN + g * 8;
        bDst[j] = smem + 8192 + (w * 4 + j) * 1024;
    }

    const int lcol = lane & 15, q = lane >> 4;
    const int wm = (w & 1) * 16, wn = (w >> 1) * 64;
    const int key = lcol & 7;                            // row&7 for all frag rows

    // fragment LDS byte offsets (swizzle folded in, loop-invariant)
    int offA[2][2], offB[2][4];
    #pragma unroll
    for (int kc = 0; kc < 2; ++kc) {
        const int gA = kc * 8 + q * 2;
        const int R  = wm + lcol;
        offA[kc][0] = (R * 64 + ((gA    ) ^ key) * 4) * 4;
        offA[kc][1] = (R * 64 + ((gA + 1) ^ key) * 4) * 4;
        #pragma unroll
        for (int ni = 0; ni < 4; ++ni) {
            const int Rb = wn + ni * 16 + lcol;
            const int gB = kc * 4 + q;
            offB[kc][ni] = 8192 + (Rb * 32 + (gB ^ key) * 4) * 4;
        }
    }

    float bcol[4];
    #pragma unroll
    for (int ni = 0; ni < 4; ++ni) bcol[ni] = bias[wn + ni * 16 + lcol];

    f32x4 acc[4] = {};
    float rsum = 0.f;

    for (int s = 0; s < 16; ++s) {
        // issue async DMA fills (prev compute finished at loop-tail barrier)
        #pragma unroll
        for (int j = 0; j < 2; ++j) load_lds16(aSrc[j] + s * 64, aDst[j]);
        #pragma unroll
        for (int j = 0; j < 4; ++j) load_lds16(bSrc[j] + s * 64, bDst[j]);
        __syncthreads();   // compiler drains vmcnt before s_barrier -> data visible

        #pragma unroll
        for (int kc = 0; kc < 2; ++kc) {
            const float4 f0 = *(const float4*)(smem + offA[kc][0]);
            const float4 f1 = *(const float4*)(smem + offA[kc][1]);
            rsum += ((f0.x + f0.y) + (f0.z + f0.w)) + ((f1.x + f1.y) + (f1.z + f1.w));
            uint4 pk;
            pk.x = pack2(f0.x, f0.y); pk.y = pack2(f0.z, f0.w);
            pk.z = pack2(f1.x, f1.y); pk.w = pack2(f1.z, f1.w);
            const bf16x8 a = *(const bf16x8*)&pk;
            #pragma unroll
            for (int ni = 0; ni < 4; ++ni) {
                const bf16x8 bb = *(const bf16x8*)(smem + offB[kc][ni]);
                acc[ni] = __builtin_amdgcn_mfma_f32_16x16x32_bf16(a, bb, acc[ni], 0, 0, 0);
            }
        }
        __syncthreads();
    }

    // rowsum: lanes sharing (lane&15) hold disjoint k-quarters of row wm+lcol
    rsum += __shfl_xor(rsum, 16);
    rsum += __shfl_xor(rsum, 32);
    if (w < 2) rs[wm + lcol] = rsum;     // waves 0,1 cover rows 0..31, no overlap
    __syncthreads();

    // epilogue: scale + bias + leaky into Clds (stride 132), then full-line store
    const int rq = q * 4;
    float sc[4];
    #pragma unroll
    for (int r = 0; r < 4; ++r) sc[r] = 1.0f / rs[wm + rq + r];
    #pragma unroll
    for (int ni = 0; ni < 4; ++ni) {
        const int col = wn + ni * 16 + lcol;
        #pragma unroll
        for (int r = 0; r < 4; ++r) {
            const int row = wm + rq + r;
            float v = acc[ni][r] * sc[r] + bcol[ni];
            v = (v >= 0.f) ? v : 0.01f * v;
            Clds[row * 132 + col] = v;
        }
    }
    __syncthreads();

    {
        float* outB = out + ((size_t)(b * NN + n0)) * FOUT;
        #pragma unroll
        for (int i = 0; i < 4; ++i) {
            const int idx = i * 256 + tid;
            const int row = idx >> 5;
            const int c4  = (idx & 31) * 4;
            *(float4*)(outB + (size_t)row * FOUT + c4) = *(const float4*)&Clds[row * 132 + c4];
        }
    }
}

extern "C" void kernel_launch(void* const* d_in, const int* in_sizes, int n_in,
                              void* d_out, int out_size, void* d_ws, size_t ws_size,
                              hipStream_t stream) {
    const float* node = (const float*)d_in[0];   // [32,1024,128]
    const float* adj  = (const float*)d_in[1];   // [32,1024,1024]
    const float* W    = (const float*)d_in[2];   // [128,128]
    const float* bias = (const float*)d_in[3];   // [128]
    float* out = (float*)d_out;                  // [32,1024,128] fp32
    unsigned short* Yt = (unsigned short*)d_ws;  // [32,128,1024] bf16 = 8 MiB

    hipLaunchKernelGGL(y_kernel,   dim3(512),  dim3(256), 0, stream, node, W, Yt);
    hipLaunchKernelGGL(gcn_kernel, dim3(1024), dim3(256), 0, stream, adj, Yt, bias, out);
}